// Round 5
// baseline (734.275 us; speedup 1.0000x reference)
//
#include <hip/hip_runtime.h>

#define NN 40000
#define NE 640000
#define DH 128
#define DO 17
#define SLOTS 64
#define CH 16      // channels per chunk
#define NCHUNK 8   // chunks; chunk c lives at hc + c*NN*CH (2.56 MB region)

// chunked layout: hc[c][n][j] = hc[(size_t)c*NN*CH + n*CH + j]

// ---------------- CSR build: fixed 64-slot rows, u16 src ----------------

__global__ void k_fill(const int* __restrict__ src, const int* __restrict__ dst,
                       int* __restrict__ cursor, unsigned short* __restrict__ csr) {
  int e = blockIdx.x * blockDim.x + threadIdx.x;
  if (e >= NE) return;
  int d = dst[e];
  int pos = atomicAdd(&cursor[d], 1);
  if (pos < SLOTS) csr[(d << 6) + pos] = (unsigned short)src[e];
}

// ---------------- x -> chunked copy ----------------

__global__ __launch_bounds__(256) void k_chunkify(const float* __restrict__ x,
                                                  float* __restrict__ out) {
  int t = blockIdx.x * 256 + threadIdx.x;  // one float4 each, NN*32 total
  if (t >= NN * 32) return;
  int n = t >> 5, q = t & 31;
  int c = q >> 2, f = q & 3;
  float4 v = *(const float4*)(x + (size_t)n * 128 + q * 4);
  *(float4*)(out + (size_t)c * NN * CH + (size_t)n * CH + f * 4) = v;
}

// ---------------- chunked mean aggregation ----------------
// block handles chunk c = bid&7 (XCD-affine if round-robin dispatch), 4 nodes
// (one per wave). Wave: 64 lanes = 4 edges x 16 channels; slots preloaded,
// distributed via shfl; 2x shfl_xor reduce. Output mean is ROW-major.

__global__ __launch_bounds__(256) void k_aggc(const float* __restrict__ hc,
                                              float* __restrict__ mean,
                                              const int* __restrict__ cursor,
                                              const unsigned short* __restrict__ csr) {
  const int bid = blockIdx.x;
  const int c = bid & 7;
  const int node = ((bid >> 3) << 2) + (threadIdx.x >> 6);
  const int lane = threadIdx.x & 63;
  const int e4 = lane >> 4;   // edge slot within iteration
  const int j = lane & 15;    // channel within chunk
  const int deg = cursor[node];
  const int cnt = deg > SLOTS ? SLOTS : deg;
  const int myslot = csr[(node << 6) + lane];  // all 64 slots, coalesced 128B
  const float* __restrict__ base = hc + (size_t)c * NN * CH;

  float acc = 0.f;
  for (int b = 0; b < cnt; b += 4) {
    int s = __shfl(myslot, b + e4);
    if (b + e4 < cnt) acc += base[(size_t)s * CH + j];
  }
  acc += __shfl_xor(acc, 16);
  acc += __shfl_xor(acc, 32);
  if (lane < 16) {
    float inv = 1.0f / (float)(deg > 0 ? deg : 1);
    mean[(size_t)node * 128 + c * CH + j] = acc * inv;
  }
}

// ---------------- fused GEMM: out = relu(Am@Wl + Hc@Wr + b) ----------------
// Am row-major mean; Hc chunked h; Hout chunked. 64x128 tile, BK=32,
// 256 threads, 4x8 micro-tile. 40000%64==0: no guards.

__global__ __launch_bounds__(256) void k_gemm(const float* __restrict__ Am,
                                              const float* __restrict__ Hc,
                                              const float* __restrict__ Wl,
                                              const float* __restrict__ Wr,
                                              const float* __restrict__ bias,
                                              float* __restrict__ Hout) {
  __shared__ float As[32][68];
  __shared__ float Ws[32][128];
  const int tid = threadIdx.x;
  const int tx = tid & 15;
  const int ty = tid >> 4;
  const int row0 = blockIdx.x * 64;

  const int lr = tid >> 2;        // 0..63 stage row
  const int lf = tid & 3;
  const int wk = tid >> 5;
  const int wc = (tid & 31) * 4;

  float acc[4][8];
#pragma unroll
  for (int i = 0; i < 4; ++i)
#pragma unroll
    for (int j = 0; j < 8; ++j) acc[i][j] = 0.f;

  for (int kc = 0; kc < 8; ++kc) {
    const float* W = (kc < 4) ? Wl : Wr;
    const int c0 = (kc & 3) * 32;
    float4 a0, a1;
    if (kc < 4) {  // mean, row-major: rows of 128, k-window c0
      a0 = *(const float4*)(Am + (size_t)(row0 + lr) * 128 + c0 + lf * 8);
      a1 = *(const float4*)(Am + (size_t)(row0 + lr) * 128 + c0 + lf * 8 + 4);
    } else {       // h, chunked: chunks 2*(kc-4), 2*(kc-4)+1; 4KB contiguous
      const int cc = (kc - 4) * 2;
      a0 = *(const float4*)(Hc + (size_t)cc * NN * CH + (size_t)(row0 + lr) * CH + lf * 4);
      a1 = *(const float4*)(Hc + (size_t)(cc + 1) * NN * CH + (size_t)(row0 + lr) * CH + lf * 4);
    }
    float4 w0 = *(const float4*)(W + (size_t)(c0 + wk) * 128 + wc);
    float4 w1 = *(const float4*)(W + (size_t)(c0 + wk + 8) * 128 + wc);
    float4 w2 = *(const float4*)(W + (size_t)(c0 + wk + 16) * 128 + wc);
    float4 w3 = *(const float4*)(W + (size_t)(c0 + wk + 24) * 128 + wc);
    __syncthreads();
    if (kc < 4) {
      const int kb = lf * 8;
      As[kb + 0][lr] = a0.x; As[kb + 1][lr] = a0.y;
      As[kb + 2][lr] = a0.z; As[kb + 3][lr] = a0.w;
      As[kb + 4][lr] = a1.x; As[kb + 5][lr] = a1.y;
      As[kb + 6][lr] = a1.z; As[kb + 7][lr] = a1.w;
    } else {
      const int f4 = lf * 4;
      As[f4 + 0][lr] = a0.x; As[f4 + 1][lr] = a0.y;
      As[f4 + 2][lr] = a0.z; As[f4 + 3][lr] = a0.w;
      As[16 + f4 + 0][lr] = a1.x; As[16 + f4 + 1][lr] = a1.y;
      As[16 + f4 + 2][lr] = a1.z; As[16 + f4 + 3][lr] = a1.w;
    }
    *(float4*)&Ws[wk][wc] = w0;
    *(float4*)&Ws[wk + 8][wc] = w1;
    *(float4*)&Ws[wk + 16][wc] = w2;
    *(float4*)&Ws[wk + 24][wc] = w3;
    __syncthreads();
#pragma unroll
    for (int k = 0; k < 32; ++k) {
      float4 a4 = *(const float4*)&As[k][ty * 4];
      float4 wa = *(const float4*)&Ws[k][tx * 8];
      float4 wb = *(const float4*)&Ws[k][tx * 8 + 4];
      const float av[4] = {a4.x, a4.y, a4.z, a4.w};
      const float wv[8] = {wa.x, wa.y, wa.z, wa.w, wb.x, wb.y, wb.z, wb.w};
#pragma unroll
      for (int i = 0; i < 4; ++i)
#pragma unroll
        for (int j = 0; j < 8; ++j) acc[i][j] = fmaf(av[i], wv[j], acc[i][j]);
    }
  }

  float bv[8];
  *(float4*)&bv[0] = *(const float4*)(bias + tx * 8);
  *(float4*)&bv[4] = *(const float4*)(bias + tx * 8 + 4);
  const int oc = tx >> 1;          // output chunk
  const int j0 = (tx & 1) * 8;     // offset within chunk
#pragma unroll
  for (int i = 0; i < 4; ++i) {
    int r = row0 + ty * 4 + i;
    float o[8];
#pragma unroll
    for (int j = 0; j < 8; ++j) {
      float v = acc[i][j] + bv[j];
      o[j] = v > 0.f ? v : 0.f;
    }
    float* op = Hout + (size_t)oc * NN * CH + (size_t)r * CH + j0;
    *(float4*)op = *(float4*)&o[0];
    *(float4*)(op + 4) = *(float4*)&o[4];
  }
}

// ---------------- layer-4 projection from chunked h ----------------

__global__ __launch_bounds__(256) void k_lastproj(const float* __restrict__ hc,
                                                  const float* __restrict__ Wl,
                                                  const float* __restrict__ Wr,
                                                  const float* __restrict__ bias,
                                                  float* __restrict__ U,
                                                  float* __restrict__ V) {
  __shared__ float As[64][132];
  const int t = threadIdx.x;
  const int row0 = blockIdx.x * 64;

#pragma unroll
  for (int c = 0; c < 8; ++c) {
    int r = t >> 2, f = t & 3;  // 64 rows x 4 float4s, coalesced per chunk
    float4 v = *(const float4*)(hc + (size_t)c * NN * CH + (size_t)(row0 + r) * CH + f * 4);
    *(float4*)&As[r][c * 16 + f * 4] = v;
  }
  __syncthreads();

  const int r = t & 63;
  const int g = t >> 6;
  const bool isV = g >= 2;
  const int st = (g & 1) ? 9 : 0;
  const int cnt = (g & 1) ? 8 : 9;
  const float* __restrict__ W = isV ? Wr : Wl;

  float acc[9];
#pragma unroll
  for (int j = 0; j < 9; ++j) {
    int jj = st + j; if (jj > 16) jj = 16;
    acc[j] = isV ? bias[jj] : 0.f;
  }

#pragma unroll 4
  for (int k4 = 0; k4 < 32; ++k4) {
    float4 a = *(const float4*)&As[r][k4 * 4];
    const float* w0 = W + (size_t)(k4 * 4) * DO + st;
#pragma unroll
    for (int j = 0; j < 9; ++j) {
      int jc = (st + j > 16) ? (16 - st) : j;
      acc[j] = fmaf(a.x, w0[jc], acc[j]);
      acc[j] = fmaf(a.y, w0[DO + jc], acc[j]);
      acc[j] = fmaf(a.z, w0[2 * DO + jc], acc[j]);
      acc[j] = fmaf(a.w, w0[3 * DO + jc], acc[j]);
    }
  }

  float* __restrict__ dstbuf = isV ? V : U;
  const size_t base = (size_t)(row0 + r) * DO + st;
#pragma unroll
  for (int j = 0; j < 9; ++j)
    if (j < cnt) dstbuf[base + j] = acc[j];
}

// ---------------- 17-dim aggregation + epilogue (layer 4) ----------------

__global__ __launch_bounds__(256) void k_agg17(const float* __restrict__ U,
                                               const float* __restrict__ V,
                                               const int* __restrict__ cursor,
                                               const unsigned short* __restrict__ csr,
                                               float* __restrict__ out) {
  int t = blockIdx.x * 256 + threadIdx.x;
  int node = t / DO;
  if (node >= NN) return;
  int ch = t - node * DO;
  int deg = cursor[node];
  int cnt = deg > SLOTS ? SLOTS : deg;
  const unsigned short* idx = csr + ((size_t)node << 6);
  float acc = 0.f;
#define GATH(S, COND) if (COND) acc += U[(size_t)(S)*DO + ch];
  for (int base = 0; base < cnt; base += 8) {
    ushort4 i0 = *(const ushort4*)(idx + base);
    ushort4 i1 = *(const ushort4*)(idx + base + 4);
    GATH(i0.x, true)
    GATH(i0.y, base + 1 < cnt)
    GATH(i0.z, base + 2 < cnt)
    GATH(i0.w, base + 3 < cnt)
    GATH(i1.x, base + 4 < cnt)
    GATH(i1.y, base + 5 < cnt)
    GATH(i1.z, base + 6 < cnt)
    GATH(i1.w, base + 7 < cnt)
  }
#undef GATH
  float inv = 1.0f / (float)(deg > 0 ? deg : 1);
  out[(size_t)node * DO + ch] = fmaxf(fmaf(acc, inv, V[(size_t)node * DO + ch]), 0.f);
}

// ---------------- launch ----------------

extern "C" void kernel_launch(void* const* d_in, const int* in_sizes, int n_in,
                              void* d_out, int out_size, void* d_ws, size_t ws_size,
                              hipStream_t stream) {
  const float* x = (const float*)d_in[0];
  const int* ei = (const int*)d_in[1];  // [2][NE] int32
  const int* src = ei;
  const int* dst = ei + NE;
  const float *wl[5], *bl[5], *wr[5];
  for (int i = 0; i < 5; ++i) {
    wl[i] = (const float*)d_in[2 + 3 * i];
    bl[i] = (const float*)d_in[3 + 3 * i];
    wr[i] = (const float*)d_in[4 + 3 * i];
  }

  char* ws = (char*)d_ws;
  int* cursor = (int*)ws;            ws += 160256;
  unsigned short* csr = (unsigned short*)ws; ws += (size_t)NN * SLOTS * 2;  // 5.12 MB
  float* A = (float*)ws;             ws += (size_t)NN * DH * 4;  // chunked
  float* B = (float*)ws;             ws += (size_t)NN * DH * 4;  // chunked
  float* M = (float*)ws;             ws += (size_t)NN * DH * 4;  // row-major mean
  float* U = M;                      // overlay: M dead by layer 4
  float* V = M + (size_t)NN * DO;

  hipMemsetAsync(cursor, 0, NN * sizeof(int), stream);
  k_fill<<<(NE + 255) / 256, 256, 0, stream>>>(src, dst, cursor, csr);
  k_chunkify<<<(NN * 32 + 255) / 256, 256, 0, stream>>>(x, A);

  const int AGG_GRID = (NN / 4) * 8;  // 80000: chunk = bid&7 (XCD-affine)
  const int GEMM_GRID = NN / 64;      // 625

  // L0
  k_aggc<<<AGG_GRID, 256, 0, stream>>>(A, M, cursor, csr);
  k_gemm<<<GEMM_GRID, 256, 0, stream>>>(M, A, wl[0], wr[0], bl[0], B);
  // L1
  k_aggc<<<AGG_GRID, 256, 0, stream>>>(B, M, cursor, csr);
  k_gemm<<<GEMM_GRID, 256, 0, stream>>>(M, B, wl[1], wr[1], bl[1], A);
  // L2
  k_aggc<<<AGG_GRID, 256, 0, stream>>>(A, M, cursor, csr);
  k_gemm<<<GEMM_GRID, 256, 0, stream>>>(M, A, wl[2], wr[2], bl[2], B);
  // L3
  k_aggc<<<AGG_GRID, 256, 0, stream>>>(B, M, cursor, csr);
  k_gemm<<<GEMM_GRID, 256, 0, stream>>>(M, B, wl[3], wr[3], bl[3], A);
  // L4
  k_lastproj<<<GEMM_GRID, 256, 0, stream>>>(A, wl[4], wr[4], bl[4], U, V);
  k_agg17<<<(NN * DO + 255) / 256, 256, 0, stream>>>(U, V, cursor, csr,
                                                     (float*)d_out);
}

// Round 6
// 638.975 us; speedup vs baseline: 1.1491x; 1.1491x over previous
//
#include <hip/hip_runtime.h>

#define NN 40000
#define NE 640000
#define DH 128
#define DO 17
#define SLOTS 64
#define CH 16      // channels per chunk (2.56 MB per chunk region: L2-resident)
#define NCHUNK 8

// chunked layout: hc[c][n][j] = hc[(size_t)c*NN*CH + n*CH + j]

// ---------------- CSR build: fixed 64-slot rows, u16 src ----------------

__global__ void k_fill(const int* __restrict__ src, const int* __restrict__ dst,
                       int* __restrict__ cursor, unsigned short* __restrict__ csr) {
  int e = blockIdx.x * blockDim.x + threadIdx.x;
  if (e >= NE) return;
  int d = dst[e];
  int pos = atomicAdd(&cursor[d], 1);
  if (pos < SLOTS) csr[(d << 6) + pos] = (unsigned short)src[e];
}

// ---------------- x -> chunked copy ----------------

__global__ __launch_bounds__(256) void k_chunkify(const float* __restrict__ x,
                                                  float* __restrict__ out) {
  int t = blockIdx.x * 256 + threadIdx.x;
  if (t >= NN * 32) return;
  int n = t >> 5, q = t & 31;
  int c = q >> 2, f = q & 3;
  float4 v = *(const float4*)(x + (size_t)n * 128 + q * 4);
  *(float4*)(out + (size_t)c * NN * CH + (size_t)n * CH + f * 4) = v;
}

// ---------------- chunked mean aggregation, float4 gathers ----------------
// chunk c = bid&7 (XCD-affine), wave = one node-chunk. Lane = edge(16) x f4(4):
// 16 edges/iteration at 16B/lane; deg~16 -> 1 iteration. Reduce: 4x shfl_xor.

__global__ __launch_bounds__(256) void k_aggc(const float* __restrict__ hc,
                                              float* __restrict__ mean,
                                              const int* __restrict__ cursor,
                                              const unsigned short* __restrict__ csr) {
  const int bid = blockIdx.x;
  const int c = bid & 7;
  const int node = ((bid >> 3) << 2) + (threadIdx.x >> 6);
  const int lane = threadIdx.x & 63;
  const int e = lane >> 2;   // edge slot within iteration (0..15)
  const int f = lane & 3;    // float4 within 64B chunk row
  const int deg = cursor[node];
  const int cnt = deg > SLOTS ? SLOTS : deg;
  const int myslot = csr[(node << 6) + lane];  // 64 slots, coalesced 128B
  const float* __restrict__ base = hc + (size_t)c * NN * CH;

  float ax = 0.f, ay = 0.f, az = 0.f, aw = 0.f;
  for (int b = 0; b < cnt; b += 16) {
    int s = __shfl(myslot, b + e);
    if (b + e < cnt) {
      float4 v = *(const float4*)(base + (size_t)s * CH + f * 4);
      ax += v.x; ay += v.y; az += v.z; aw += v.w;
    }
  }
#pragma unroll
  for (int m = 4; m <= 32; m <<= 1) {
    ax += __shfl_xor(ax, m);
    ay += __shfl_xor(ay, m);
    az += __shfl_xor(az, m);
    aw += __shfl_xor(aw, m);
  }
  if (lane < 4) {
    float inv = 1.0f / (float)(deg > 0 ? deg : 1);
    float4 o; o.x = ax * inv; o.y = ay * inv; o.z = az * inv; o.w = aw * inv;
    *(float4*)(mean + (size_t)node * 128 + c * CH + lane * 4) = o;
  }
}

// ---------------- fused GEMM: out = relu(Am@Wl + Hc@Wr + b) ----------------

__global__ __launch_bounds__(256) void k_gemm(const float* __restrict__ Am,
                                              const float* __restrict__ Hc,
                                              const float* __restrict__ Wl,
                                              const float* __restrict__ Wr,
                                              const float* __restrict__ bias,
                                              float* __restrict__ Hout) {
  __shared__ float As[32][68];
  __shared__ float Ws[32][128];
  const int tid = threadIdx.x;
  const int tx = tid & 15;
  const int ty = tid >> 4;
  const int row0 = blockIdx.x * 64;

  const int lr = tid >> 2;
  const int lf = tid & 3;
  const int wk = tid >> 5;
  const int wc = (tid & 31) * 4;

  float acc[4][8];
#pragma unroll
  for (int i = 0; i < 4; ++i)
#pragma unroll
    for (int j = 0; j < 8; ++j) acc[i][j] = 0.f;

  for (int kc = 0; kc < 8; ++kc) {
    const float* W = (kc < 4) ? Wl : Wr;
    const int c0 = (kc & 3) * 32;
    float4 a0, a1;
    if (kc < 4) {
      a0 = *(const float4*)(Am + (size_t)(row0 + lr) * 128 + c0 + lf * 8);
      a1 = *(const float4*)(Am + (size_t)(row0 + lr) * 128 + c0 + lf * 8 + 4);
    } else {
      const int cc = (kc - 4) * 2;
      a0 = *(const float4*)(Hc + (size_t)cc * NN * CH + (size_t)(row0 + lr) * CH + lf * 4);
      a1 = *(const float4*)(Hc + (size_t)(cc + 1) * NN * CH + (size_t)(row0 + lr) * CH + lf * 4);
    }
    float4 w0 = *(const float4*)(W + (size_t)(c0 + wk) * 128 + wc);
    float4 w1 = *(const float4*)(W + (size_t)(c0 + wk + 8) * 128 + wc);
    float4 w2 = *(const float4*)(W + (size_t)(c0 + wk + 16) * 128 + wc);
    float4 w3 = *(const float4*)(W + (size_t)(c0 + wk + 24) * 128 + wc);
    __syncthreads();
    if (kc < 4) {
      const int kb = lf * 8;
      As[kb + 0][lr] = a0.x; As[kb + 1][lr] = a0.y;
      As[kb + 2][lr] = a0.z; As[kb + 3][lr] = a0.w;
      As[kb + 4][lr] = a1.x; As[kb + 5][lr] = a1.y;
      As[kb + 6][lr] = a1.z; As[kb + 7][lr] = a1.w;
    } else {
      const int f4 = lf * 4;
      As[f4 + 0][lr] = a0.x; As[f4 + 1][lr] = a0.y;
      As[f4 + 2][lr] = a0.z; As[f4 + 3][lr] = a0.w;
      As[16 + f4 + 0][lr] = a1.x; As[16 + f4 + 1][lr] = a1.y;
      As[16 + f4 + 2][lr] = a1.z; As[16 + f4 + 3][lr] = a1.w;
    }
    *(float4*)&Ws[wk][wc] = w0;
    *(float4*)&Ws[wk + 8][wc] = w1;
    *(float4*)&Ws[wk + 16][wc] = w2;
    *(float4*)&Ws[wk + 24][wc] = w3;
    __syncthreads();
#pragma unroll
    for (int k = 0; k < 32; ++k) {
      float4 a4 = *(const float4*)&As[k][ty * 4];
      float4 wa = *(const float4*)&Ws[k][tx * 8];
      float4 wb = *(const float4*)&Ws[k][tx * 8 + 4];
      const float av[4] = {a4.x, a4.y, a4.z, a4.w};
      const float wv[8] = {wa.x, wa.y, wa.z, wa.w, wb.x, wb.y, wb.z, wb.w};
#pragma unroll
      for (int i = 0; i < 4; ++i)
#pragma unroll
        for (int j = 0; j < 8; ++j) acc[i][j] = fmaf(av[i], wv[j], acc[i][j]);
    }
  }

  float bv[8];
  *(float4*)&bv[0] = *(const float4*)(bias + tx * 8);
  *(float4*)&bv[4] = *(const float4*)(bias + tx * 8 + 4);
  const int oc = tx >> 1;
  const int j0 = (tx & 1) * 8;
#pragma unroll
  for (int i = 0; i < 4; ++i) {
    int r = row0 + ty * 4 + i;
    float o[8];
#pragma unroll
    for (int j = 0; j < 8; ++j) {
      float v = acc[i][j] + bv[j];
      o[j] = v > 0.f ? v : 0.f;
    }
    float* op = Hout + (size_t)oc * NN * CH + (size_t)r * CH + j0;
    *(float4*)op = *(float4*)&o[0];
    *(float4*)(op + 4) = *(float4*)&o[4];
  }
}

// ---------------- layer-4 projection from chunked h ----------------

__global__ __launch_bounds__(256) void k_lastproj(const float* __restrict__ hc,
                                                  const float* __restrict__ Wl,
                                                  const float* __restrict__ Wr,
                                                  const float* __restrict__ bias,
                                                  float* __restrict__ U,
                                                  float* __restrict__ V) {
  __shared__ float As[64][132];
  const int t = threadIdx.x;
  const int row0 = blockIdx.x * 64;

#pragma unroll
  for (int c = 0; c < 8; ++c) {
    int r = t >> 2, f = t & 3;
    float4 v = *(const float4*)(hc + (size_t)c * NN * CH + (size_t)(row0 + r) * CH + f * 4);
    *(float4*)&As[r][c * 16 + f * 4] = v;
  }
  __syncthreads();

  const int r = t & 63;
  const int g = t >> 6;
  const bool isV = g >= 2;
  const int st = (g & 1) ? 9 : 0;
  const int cnt = (g & 1) ? 8 : 9;
  const float* __restrict__ W = isV ? Wr : Wl;

  float acc[9];
#pragma unroll
  for (int j = 0; j < 9; ++j) {
    int jj = st + j; if (jj > 16) jj = 16;
    acc[j] = isV ? bias[jj] : 0.f;
  }

#pragma unroll 4
  for (int k4 = 0; k4 < 32; ++k4) {
    float4 a = *(const float4*)&As[r][k4 * 4];
    const float* w0 = W + (size_t)(k4 * 4) * DO + st;
#pragma unroll
    for (int j = 0; j < 9; ++j) {
      int jc = (st + j > 16) ? (16 - st) : j;
      acc[j] = fmaf(a.x, w0[jc], acc[j]);
      acc[j] = fmaf(a.y, w0[DO + jc], acc[j]);
      acc[j] = fmaf(a.z, w0[2 * DO + jc], acc[j]);
      acc[j] = fmaf(a.w, w0[3 * DO + jc], acc[j]);
    }
  }

  float* __restrict__ dstbuf = isV ? V : U;
  const size_t base = (size_t)(row0 + r) * DO + st;
#pragma unroll
  for (int j = 0; j < 9; ++j)
    if (j < cnt) dstbuf[base + j] = acc[j];
}

// ---------------- 17-dim aggregation + epilogue (layer 4) ----------------

__global__ __launch_bounds__(256) void k_agg17(const float* __restrict__ U,
                                               const float* __restrict__ V,
                                               const int* __restrict__ cursor,
                                               const unsigned short* __restrict__ csr,
                                               float* __restrict__ out) {
  int t = blockIdx.x * 256 + threadIdx.x;
  int node = t / DO;
  if (node >= NN) return;
  int ch = t - node * DO;
  int deg = cursor[node];
  int cnt = deg > SLOTS ? SLOTS : deg;
  const unsigned short* idx = csr + ((size_t)node << 6);
  float acc = 0.f;
#define GATH(S, COND) if (COND) acc += U[(size_t)(S)*DO + ch];
  for (int base = 0; base < cnt; base += 8) {
    ushort4 i0 = *(const ushort4*)(idx + base);
    ushort4 i1 = *(const ushort4*)(idx + base + 4);
    GATH(i0.x, true)
    GATH(i0.y, base + 1 < cnt)
    GATH(i0.z, base + 2 < cnt)
    GATH(i0.w, base + 3 < cnt)
    GATH(i1.x, base + 4 < cnt)
    GATH(i1.y, base + 5 < cnt)
    GATH(i1.z, base + 6 < cnt)
    GATH(i1.w, base + 7 < cnt)
  }
#undef GATH
  float inv = 1.0f / (float)(deg > 0 ? deg : 1);
  out[(size_t)node * DO + ch] = fmaxf(fmaf(acc, inv, V[(size_t)node * DO + ch]), 0.f);
}

// ---------------- launch ----------------

extern "C" void kernel_launch(void* const* d_in, const int* in_sizes, int n_in,
                              void* d_out, int out_size, void* d_ws, size_t ws_size,
                              hipStream_t stream) {
  const float* x = (const float*)d_in[0];
  const int* ei = (const int*)d_in[1];  // [2][NE] int32
  const int* src = ei;
  const int* dst = ei + NE;
  const float *wl[5], *bl[5], *wr[5];
  for (int i = 0; i < 5; ++i) {
    wl[i] = (const float*)d_in[2 + 3 * i];
    bl[i] = (const float*)d_in[3 + 3 * i];
    wr[i] = (const float*)d_in[4 + 3 * i];
  }

  char* ws = (char*)d_ws;
  int* cursor = (int*)ws;            ws += 160256;
  unsigned short* csr = (unsigned short*)ws; ws += (size_t)NN * SLOTS * 2;
  float* A = (float*)ws;             ws += (size_t)NN * DH * 4;  // chunked
  float* B = (float*)ws;             ws += (size_t)NN * DH * 4;  // chunked
  float* M = (float*)ws;             ws += (size_t)NN * DH * 4;  // row-major mean
  float* U = M;
  float* V = M + (size_t)NN * DO;

  hipMemsetAsync(cursor, 0, NN * sizeof(int), stream);
  k_fill<<<(NE + 255) / 256, 256, 0, stream>>>(src, dst, cursor, csr);
  k_chunkify<<<(NN * 32 + 255) / 256, 256, 0, stream>>>(x, A);

  const int AGG_GRID = (NN / 4) * 8;  // chunk = bid&7 (XCD-affine)
  const int GEMM_GRID = NN / 64;

  // L0
  k_aggc<<<AGG_GRID, 256, 0, stream>>>(A, M, cursor, csr);
  k_gemm<<<GEMM_GRID, 256, 0, stream>>>(M, A, wl[0], wr[0], bl[0], B);
  // L1
  k_aggc<<<AGG_GRID, 256, 0, stream>>>(B, M, cursor, csr);
  k_gemm<<<GEMM_GRID, 256, 0, stream>>>(M, B, wl[1], wr[1], bl[1], A);
  // L2
  k_aggc<<<AGG_GRID, 256, 0, stream>>>(A, M, cursor, csr);
  k_gemm<<<GEMM_GRID, 256, 0, stream>>>(M, A, wl[2], wr[2], bl[2], B);
  // L3
  k_aggc<<<AGG_GRID, 256, 0, stream>>>(B, M, cursor, csr);
  k_gemm<<<GEMM_GRID, 256, 0, stream>>>(M, B, wl[3], wr[3], bl[3], A);
  // L4
  k_lastproj<<<GEMM_GRID, 256, 0, stream>>>(A, wl[4], wr[4], bl[4], U, V);
  k_agg17<<<(NN * DO + 255) / 256, 256, 0, stream>>>(U, V, cursor, csr,
                                                     (float*)d_out);
}

// Round 8
// 473.707 us; speedup vs baseline: 1.5501x; 1.3489x over previous
//
#include <hip/hip_runtime.h>

#define NN 40000
#define NE 640000
#define DH 128
#define DO 17
#define SLOTS 64

__device__ inline float b2f(unsigned short u) {
  union { unsigned int i; float f; } c;
  c.i = (unsigned int)u << 16;
  return c.f;
}
__device__ inline unsigned short f2b(float f) {
  union { float f; unsigned int i; } c;
  c.f = f;
  unsigned int r = c.i + 0x7fff + ((c.i >> 16) & 1);  // RNE
  return (unsigned short)(r >> 16);
}

// ---------------- CSR build: fixed 64-slot rows, u16 src ----------------

__global__ void k_fill(const int* __restrict__ src, const int* __restrict__ dst,
                       int* __restrict__ cursor, unsigned short* __restrict__ csr) {
  int e = blockIdx.x * blockDim.x + threadIdx.x;
  if (e >= NE) return;
  int d = dst[e];
  int pos = atomicAdd(&cursor[d], 1);
  if (pos < SLOTS) csr[(d << 6) + pos] = (unsigned short)src[e];
}

// ---------------- x -> bf16 mirror ----------------

__global__ __launch_bounds__(256) void k_tobf16(const float* __restrict__ x,
                                                unsigned short* __restrict__ xb) {
  int t = blockIdx.x * 256 + threadIdx.x;  // one float4 -> ushort4 each
  if (t >= NN * 32) return;
  float4 v = *(const float4*)(x + (size_t)t * 4);
  ushort4 o;
  o.x = f2b(v.x); o.y = f2b(v.y); o.z = f2b(v.z); o.w = f2b(v.w);
  *(ushort4*)(xb + (size_t)t * 4) = o;
}

// ---------------- mean aggregation: bf16 rows, 2 nodes/wave ----------------
// lane = 32 channels-of-4; 8B/lane x 32 = 256B row. 8 independent gathers/iter.

__global__ __launch_bounds__(256) void k_agg(const unsigned short* __restrict__ in,
                                             float* __restrict__ mean,
                                             const int* __restrict__ cursor,
                                             const unsigned short* __restrict__ csr) {
  int t = blockIdx.x * 256 + threadIdx.x;
  int node = t >> 5;
  if (node >= NN) return;
  int ch = threadIdx.x & 31;
  int deg = cursor[node];
  int cnt = deg > SLOTS ? SLOTS : deg;
  const ushort4* in4 = (const ushort4*)in;
  const unsigned short* idx = csr + ((size_t)node << 6);
  float ax = 0.f, ay = 0.f, az = 0.f, aw = 0.f;

#define GATH(S, COND)                                    \
  if (COND) {                                            \
    ushort4 v = in4[(size_t)(S)*32 + ch];                \
    ax += b2f(v.x); ay += b2f(v.y);                      \
    az += b2f(v.z); aw += b2f(v.w);                      \
  }

  for (int base = 0; base < cnt; base += 8) {
    ushort4 i0 = *(const ushort4*)(idx + base);
    ushort4 i1 = *(const ushort4*)(idx + base + 4);
    GATH(i0.x, true)
    GATH(i0.y, base + 1 < cnt)
    GATH(i0.z, base + 2 < cnt)
    GATH(i0.w, base + 3 < cnt)
    GATH(i1.x, base + 4 < cnt)
    GATH(i1.y, base + 5 < cnt)
    GATH(i1.z, base + 6 < cnt)
    GATH(i1.w, base + 7 < cnt)
  }
#undef GATH
  float inv = 1.0f / (float)(deg > 0 ? deg : 1);
  float4 o; o.x = ax * inv; o.y = ay * inv; o.z = az * inv; o.w = aw * inv;
  *(float4*)(mean + (size_t)node * 128 + ch * 4) = o;
}

// ---------------- fused GEMM: relu(Am@Wl + Ah@Wr + b) -> fp32 + bf16 ----------------
// 64x128 tile, BK=32, 256 threads, 4x8 micro-tile. 40000%64==0: no guards.

__global__ __launch_bounds__(256) void k_gemm(const float* __restrict__ Am,
                                              const float* __restrict__ Ah,
                                              const float* __restrict__ Wl,
                                              const float* __restrict__ Wr,
                                              const float* __restrict__ bias,
                                              float* __restrict__ Hout,
                                              unsigned short* __restrict__ Hb) {
  __shared__ float As[32][68];
  __shared__ float Ws[32][128];
  const int tid = threadIdx.x;
  const int tx = tid & 15;
  const int ty = tid >> 4;
  const int row0 = blockIdx.x * 64;

  const int lr = tid >> 2;
  const int lf = tid & 3;
  const int wk = tid >> 5;
  const int wc = (tid & 31) * 4;

  float acc[4][8];
#pragma unroll
  for (int i = 0; i < 4; ++i)
#pragma unroll
    for (int j = 0; j < 8; ++j) acc[i][j] = 0.f;

  for (int kc = 0; kc < 8; ++kc) {
    const float* A = (kc < 4) ? Am : Ah;
    const float* W = (kc < 4) ? Wl : Wr;
    const int c0 = (kc & 3) * 32;
    float4 a0 = *(const float4*)(A + (size_t)(row0 + lr) * 128 + c0 + lf * 8);
    float4 a1 = *(const float4*)(A + (size_t)(row0 + lr) * 128 + c0 + lf * 8 + 4);
    float4 w0 = *(const float4*)(W + (size_t)(c0 + wk) * 128 + wc);
    float4 w1 = *(const float4*)(W + (size_t)(c0 + wk + 8) * 128 + wc);
    float4 w2 = *(const float4*)(W + (size_t)(c0 + wk + 16) * 128 + wc);
    float4 w3 = *(const float4*)(W + (size_t)(c0 + wk + 24) * 128 + wc);
    __syncthreads();
    {
      const int kb = lf * 8;
      As[kb + 0][lr] = a0.x; As[kb + 1][lr] = a0.y;
      As[kb + 2][lr] = a0.z; As[kb + 3][lr] = a0.w;
      As[kb + 4][lr] = a1.x; As[kb + 5][lr] = a1.y;
      As[kb + 6][lr] = a1.z; As[kb + 7][lr] = a1.w;
    }
    *(float4*)&Ws[wk][wc] = w0;
    *(float4*)&Ws[wk + 8][wc] = w1;
    *(float4*)&Ws[wk + 16][wc] = w2;
    *(float4*)&Ws[wk + 24][wc] = w3;
    __syncthreads();
#pragma unroll
    for (int k = 0; k < 32; ++k) {
      float4 a4 = *(const float4*)&As[k][ty * 4];
      float4 wa = *(const float4*)&Ws[k][tx * 8];
      float4 wb = *(const float4*)&Ws[k][tx * 8 + 4];
      const float av[4] = {a4.x, a4.y, a4.z, a4.w};
      const float wv[8] = {wa.x, wa.y, wa.z, wa.w, wb.x, wb.y, wb.z, wb.w};
#pragma unroll
      for (int i = 0; i < 4; ++i)
#pragma unroll
        for (int j = 0; j < 8; ++j) acc[i][j] = fmaf(av[i], wv[j], acc[i][j]);
    }
  }

  float bv[8];
  *(float4*)&bv[0] = *(const float4*)(bias + tx * 8);
  *(float4*)&bv[4] = *(const float4*)(bias + tx * 8 + 4);
#pragma unroll
  for (int i = 0; i < 4; ++i) {
    int r = row0 + ty * 4 + i;
    float o[8];
    union { ushort4 q[2]; uint4 v; } pk;
#pragma unroll
    for (int j = 0; j < 8; ++j) {
      float v = acc[i][j] + bv[j];
      o[j] = v > 0.f ? v : 0.f;
    }
    pk.q[0].x = f2b(o[0]); pk.q[0].y = f2b(o[1]);
    pk.q[0].z = f2b(o[2]); pk.q[0].w = f2b(o[3]);
    pk.q[1].x = f2b(o[4]); pk.q[1].y = f2b(o[5]);
    pk.q[1].z = f2b(o[6]); pk.q[1].w = f2b(o[7]);
    *(float4*)(Hout + (size_t)r * 128 + tx * 8) = *(float4*)&o[0];
    *(float4*)(Hout + (size_t)r * 128 + tx * 8 + 4) = *(float4*)&o[4];
    *(uint4*)(Hb + (size_t)r * 128 + tx * 8) = pk.v;
  }
}

// ---------------- layer-4 projection (row-major h) ----------------

__global__ __launch_bounds__(256) void k_lastproj(const float* __restrict__ h,
                                                  const float* __restrict__ Wl,
                                                  const float* __restrict__ Wr,
                                                  const float* __restrict__ bias,
                                                  float* __restrict__ U,
                                                  float* __restrict__ V) {
  __shared__ float As[64][132];
  const int t = threadIdx.x;
  const int row0 = blockIdx.x * 64;

  // stage 64 rows x 128 cols = 2048 float4s; 8 per thread, coalesced
#pragma unroll
  for (int i = 0; i < 8; ++i) {
    int idx = i * 256 + t;
    int r = idx >> 5, c4 = idx & 31;   // 32 float4s per row
    float4 v = *(const float4*)(h + (size_t)(row0 + r) * 128 + c4 * 4);
    *(float4*)&As[r][c4 * 4] = v;
  }
  __syncthreads();

  const int r = t & 63;
  const int g = t >> 6;
  const bool isV = g >= 2;
  const int st = (g & 1) ? 9 : 0;
  const int cnt = (g & 1) ? 8 : 9;
  const float* __restrict__ W = isV ? Wr : Wl;

  float acc[9];
#pragma unroll
  for (int j = 0; j < 9; ++j) {
    int jj = st + j; if (jj > 16) jj = 16;
    acc[j] = isV ? bias[jj] : 0.f;
  }

#pragma unroll 4
  for (int k4 = 0; k4 < 32; ++k4) {
    float4 a = *(const float4*)&As[r][k4 * 4];
    const float* w0 = W + (size_t)(k4 * 4) * DO + st;
#pragma unroll
    for (int j = 0; j < 9; ++j) {
      int jc = (st + j > 16) ? (16 - st) : j;
      acc[j] = fmaf(a.x, w0[jc], acc[j]);
      acc[j] = fmaf(a.y, w0[DO + jc], acc[j]);
      acc[j] = fmaf(a.z, w0[2 * DO + jc], acc[j]);
      acc[j] = fmaf(a.w, w0[3 * DO + jc], acc[j]);
    }
  }

  float* __restrict__ dstbuf = isV ? V : U;
  const size_t base = (size_t)(row0 + r) * DO + st;
#pragma unroll
  for (int j = 0; j < 9; ++j)
    if (j < cnt) dstbuf[base + j] = acc[j];
}

// ---------------- 17-dim aggregation + epilogue (layer 4) ----------------

__global__ __launch_bounds__(256) void k_agg17(const float* __restrict__ U,
                                               const float* __restrict__ V,
                                               const int* __restrict__ cursor,
                                               const unsigned short* __restrict__ csr,
                                               float* __restrict__ out) {
  int t = blockIdx.x * 256 + threadIdx.x;
  int node = t / DO;
  if (node >= NN) return;
  int ch = t - node * DO;
  int deg = cursor[node];
  int cnt = deg > SLOTS ? SLOTS : deg;
  const unsigned short* idx = csr + ((size_t)node << 6);
  float acc = 0.f;
#define GATH(S, COND) if (COND) acc += U[(size_t)(S)*DO + ch];
  for (int base = 0; base < cnt; base += 8) {
    ushort4 i0 = *(const ushort4*)(idx + base);
    ushort4 i1 = *(const ushort4*)(idx + base + 4);
    GATH(i0.x, true)
    GATH(i0.y, base + 1 < cnt)
    GATH(i0.z, base + 2 < cnt)
    GATH(i0.w, base + 3 < cnt)
    GATH(i1.x, base + 4 < cnt)
    GATH(i1.y, base + 5 < cnt)
    GATH(i1.z, base + 6 < cnt)
    GATH(i1.w, base + 7 < cnt)
  }
#undef GATH
  float inv = 1.0f / (float)(deg > 0 ? deg : 1);
  out[(size_t)node * DO + ch] = fmaxf(fmaf(acc, inv, V[(size_t)node * DO + ch]), 0.f);
}

// ---------------- launch ----------------

extern "C" void kernel_launch(void* const* d_in, const int* in_sizes, int n_in,
                              void* d_out, int out_size, void* d_ws, size_t ws_size,
                              hipStream_t stream) {
  const float* x = (const float*)d_in[0];
  const int* ei = (const int*)d_in[1];  // [2][NE] int32
  const int* src = ei;
  const int* dst = ei + NE;
  const float *wl[5], *bl[5], *wr[5];
  for (int i = 0; i < 5; ++i) {
    wl[i] = (const float*)d_in[2 + 3 * i];
    bl[i] = (const float*)d_in[3 + 3 * i];
    wr[i] = (const float*)d_in[4 + 3 * i];
  }

  char* ws = (char*)d_ws;
  int* cursor = (int*)ws;                     ws += 160256;
  unsigned short* csr = (unsigned short*)ws;  ws += (size_t)NN * SLOTS * 2;  // 5.12 MB
  unsigned short* B16 = (unsigned short*)ws;  ws += (size_t)NN * DH * 2;     // 10.24 MB
  float* P = (float*)ws;                      ws += (size_t)NN * DH * 4;
  float* Q = (float*)ws;                      ws += (size_t)NN * DH * 4;
  float* M = (float*)ws;                      ws += (size_t)NN * DH * 4;
  float* U = M;   // M dead by layer 4
  float* V = M + (size_t)NN * DO;

  hipMemsetAsync(cursor, 0, NN * sizeof(int), stream);
  k_fill<<<(NE + 255) / 256, 256, 0, stream>>>(src, dst, cursor, csr);
  k_tobf16<<<(NN * 32 + 255) / 256, 256, 0, stream>>>(x, B16);

  const int AGG_GRID = (NN * 32 + 255) / 256;  // 5000
  const int GEMM_GRID = NN / 64;               // 625

  // L0
  k_agg<<<AGG_GRID, 256, 0, stream>>>(B16, M, cursor, csr);
  k_gemm<<<GEMM_GRID, 256, 0, stream>>>(M, x, wl[0], wr[0], bl[0], P, B16);
  // L1
  k_agg<<<AGG_GRID, 256, 0, stream>>>(B16, M, cursor, csr);
  k_gemm<<<GEMM_GRID, 256, 0, stream>>>(M, P, wl[1], wr[1], bl[1], Q, B16);
  // L2
  k_agg<<<AGG_GRID, 256, 0, stream>>>(B16, M, cursor, csr);
  k_gemm<<<GEMM_GRID, 256, 0, stream>>>(M, Q, wl[2], wr[2], bl[2], P, B16);
  // L3
  k_agg<<<AGG_GRID, 256, 0, stream>>>(B16, M, cursor, csr);
  k_gemm<<<GEMM_GRID, 256, 0, stream>>>(M, P, wl[3], wr[3], bl[3], Q, B16);
  // L4
  k_lastproj<<<GEMM_GRID, 256, 0, stream>>>(Q, wl[4], wr[4], bl[4], U, V);
  k_agg17<<<(NN * DO + 255) / 256, 256, 0, stream>>>(U, V, cursor, csr,
                                                     (float*)d_out);
}

// Round 9
// 403.523 us; speedup vs baseline: 1.8197x; 1.1739x over previous
//
#include <hip/hip_runtime.h>

#define NN 40000
#define NE 640000
#define DH 128
#define DO 17
#define SLOTS 64

typedef __attribute__((ext_vector_type(8))) short short8v;
typedef __attribute__((ext_vector_type(4))) float f32x4;

__device__ inline float b2f(unsigned short u) {
  union { unsigned int i; float f; } c;
  c.i = (unsigned int)u << 16;
  return c.f;
}
__device__ inline unsigned short f2b(float f) {
  union { float f; unsigned int i; } c;
  c.f = f;
  unsigned int r = c.i + 0x7fff + ((c.i >> 16) & 1);  // RNE
  return (unsigned short)(r >> 16);
}

// ---------------- CSR build ----------------

__global__ void k_fill(const int* __restrict__ src, const int* __restrict__ dst,
                       int* __restrict__ cursor, unsigned short* __restrict__ csr) {
  int e = blockIdx.x * blockDim.x + threadIdx.x;
  if (e >= NE) return;
  int d = dst[e];
  int pos = atomicAdd(&cursor[d], 1);
  if (pos < SLOTS) csr[(d << 6) + pos] = (unsigned short)src[e];
}

// ---------------- x -> hi/lo bf16 planes ----------------

__global__ __launch_bounds__(256) void k_tobf16(const float* __restrict__ x,
                                                unsigned short* __restrict__ hi,
                                                unsigned short* __restrict__ lo) {
  int t = blockIdx.x * 256 + threadIdx.x;
  if (t >= NN * 32) return;
  float4 v = *(const float4*)(x + (size_t)t * 4);
  ushort4 h, l;
  h.x = f2b(v.x); l.x = f2b(v.x - b2f(h.x));
  h.y = f2b(v.y); l.y = f2b(v.y - b2f(h.y));
  h.z = f2b(v.z); l.z = f2b(v.z - b2f(h.z));
  h.w = f2b(v.w); l.w = f2b(v.w - b2f(h.w));
  *(ushort4*)(hi + (size_t)t * 4) = h;
  *(ushort4*)(lo + (size_t)t * 4) = l;
}

// ---------------- weight transpose + split: WT[n][k], k in [Wl;Wr] ----------------

__global__ __launch_bounds__(256) void k_splitw(const float* __restrict__ Wl,
                                                const float* __restrict__ Wr,
                                                unsigned short* __restrict__ Thi,
                                                unsigned short* __restrict__ Tlo) {
  int n = blockIdx.x;   // 0..127
  int k = threadIdx.x;  // 0..255
  float v = (k < 128) ? Wl[(size_t)k * 128 + n] : Wr[(size_t)(k - 128) * 128 + n];
  unsigned short hi = f2b(v);
  unsigned short lo = f2b(v - b2f(hi));
  Thi[(size_t)n * 256 + k] = hi;
  Tlo[(size_t)n * 256 + k] = lo;
}

// ---------------- mean aggregation: bf16 rows, 2 nodes/wave ----------------

__global__ __launch_bounds__(256) void k_agg(const unsigned short* __restrict__ in,
                                             float* __restrict__ mean,
                                             const int* __restrict__ cursor,
                                             const unsigned short* __restrict__ csr) {
  int t = blockIdx.x * 256 + threadIdx.x;
  int node = t >> 5;
  if (node >= NN) return;
  int ch = threadIdx.x & 31;
  int deg = cursor[node];
  int cnt = deg > SLOTS ? SLOTS : deg;
  const ushort4* in4 = (const ushort4*)in;
  const unsigned short* idx = csr + ((size_t)node << 6);
  float ax = 0.f, ay = 0.f, az = 0.f, aw = 0.f;

#define GATH(S, COND)                                    \
  if (COND) {                                            \
    ushort4 v = in4[(size_t)(S)*32 + ch];                \
    ax += b2f(v.x); ay += b2f(v.y);                      \
    az += b2f(v.z); aw += b2f(v.w);                      \
  }

  for (int base = 0; base < cnt; base += 8) {
    ushort4 i0 = *(const ushort4*)(idx + base);
    ushort4 i1 = *(const ushort4*)(idx + base + 4);
    GATH(i0.x, true)
    GATH(i0.y, base + 1 < cnt)
    GATH(i0.z, base + 2 < cnt)
    GATH(i0.w, base + 3 < cnt)
    GATH(i1.x, base + 4 < cnt)
    GATH(i1.y, base + 5 < cnt)
    GATH(i1.z, base + 6 < cnt)
    GATH(i1.w, base + 7 < cnt)
  }
#undef GATH
  float inv = 1.0f / (float)(deg > 0 ? deg : 1);
  float4 o; o.x = ax * inv; o.y = ay * inv; o.z = az * inv; o.w = aw * inv;
  *(float4*)(mean + (size_t)node * 128 + ch * 4) = o;
}

// ---------------- MFMA GEMM: h' = relu([M|h] @ WT^T + b), split-bf16 ----------------
// BM=32, BN=128, 256 thr (4 waves), 1250 blocks. In-place h update (block owns rows).

__global__ __launch_bounds__(256) void k_gemm_mfma(
    const float* __restrict__ Mn,
    const unsigned short* Hhi, const unsigned short* Hlo,   // no restrict: alias out
    const unsigned short* __restrict__ WThi,
    const unsigned short* __restrict__ WTlo,
    const float* __restrict__ bias,
    unsigned short* Ohi, unsigned short* Olo) {
  __shared__ unsigned short Ah[32][40];   // pad 40 ushorts = 80B rows (16B-aligned)
  __shared__ unsigned short Al[32][40];
  __shared__ unsigned short Bh[128][40];
  __shared__ unsigned short Bl[128][40];
  const int tid = threadIdx.x;
  const int row0 = blockIdx.x * 32;
  const int w = tid >> 6;
  const int lane = tid & 63;
  const int li = lane & 15;
  const int lg = lane >> 4;

  f32x4 acc00 = {0.f, 0.f, 0.f, 0.f};
  f32x4 acc01 = acc00, acc10 = acc00, acc11 = acc00;

  const int ar = tid >> 3, af = tid & 7;         // A stage: row, float4 idx
  const int bc = tid >> 1, bs = (tid & 1) * 16;  // B stage: col, seg

  for (int kc = 0; kc < 8; ++kc) {
    ushort4 a_hi, a_lo;
    if (kc < 4) {
      float4 v = *(const float4*)(Mn + (size_t)(row0 + ar) * 128 + kc * 32 + af * 4);
      a_hi.x = f2b(v.x); a_lo.x = f2b(v.x - b2f(a_hi.x));
      a_hi.y = f2b(v.y); a_lo.y = f2b(v.y - b2f(a_hi.y));
      a_hi.z = f2b(v.z); a_lo.z = f2b(v.z - b2f(a_hi.z));
      a_hi.w = f2b(v.w); a_lo.w = f2b(v.w - b2f(a_hi.w));
    } else {
      size_t off = (size_t)(row0 + ar) * 128 + (kc - 4) * 32 + af * 4;
      a_hi = *(const ushort4*)(Hhi + off);
      a_lo = *(const ushort4*)(Hlo + off);
    }
    size_t woff = (size_t)bc * 256 + kc * 32 + bs;
    uint4 b_h0 = *(const uint4*)(WThi + woff);
    uint4 b_h1 = *(const uint4*)(WThi + woff + 8);
    uint4 b_l0 = *(const uint4*)(WTlo + woff);
    uint4 b_l1 = *(const uint4*)(WTlo + woff + 8);
    __syncthreads();
    *(ushort4*)&Ah[ar][af * 4] = a_hi;
    *(ushort4*)&Al[ar][af * 4] = a_lo;
    *(uint4*)&Bh[bc][bs] = b_h0;
    *(uint4*)&Bh[bc][bs + 8] = b_h1;
    *(uint4*)&Bl[bc][bs] = b_l0;
    *(uint4*)&Bl[bc][bs + 8] = b_l1;
    __syncthreads();
    short8v a0h = *(const short8v*)&Ah[li][lg * 8];
    short8v a1h = *(const short8v*)&Ah[16 + li][lg * 8];
    short8v a0l = *(const short8v*)&Al[li][lg * 8];
    short8v a1l = *(const short8v*)&Al[16 + li][lg * 8];
    short8v b0h = *(const short8v*)&Bh[w * 32 + li][lg * 8];
    short8v b1h = *(const short8v*)&Bh[w * 32 + 16 + li][lg * 8];
    short8v b0l = *(const short8v*)&Bl[w * 32 + li][lg * 8];
    short8v b1l = *(const short8v*)&Bl[w * 32 + 16 + li][lg * 8];
    acc00 = __builtin_amdgcn_mfma_f32_16x16x32_bf16(a0h, b0h, acc00, 0, 0, 0);
    acc00 = __builtin_amdgcn_mfma_f32_16x16x32_bf16(a0l, b0h, acc00, 0, 0, 0);
    acc00 = __builtin_amdgcn_mfma_f32_16x16x32_bf16(a0h, b0l, acc00, 0, 0, 0);
    acc01 = __builtin_amdgcn_mfma_f32_16x16x32_bf16(a0h, b1h, acc01, 0, 0, 0);
    acc01 = __builtin_amdgcn_mfma_f32_16x16x32_bf16(a0l, b1h, acc01, 0, 0, 0);
    acc01 = __builtin_amdgcn_mfma_f32_16x16x32_bf16(a0h, b1l, acc01, 0, 0, 0);
    acc10 = __builtin_amdgcn_mfma_f32_16x16x32_bf16(a1h, b0h, acc10, 0, 0, 0);
    acc10 = __builtin_amdgcn_mfma_f32_16x16x32_bf16(a1l, b0h, acc10, 0, 0, 0);
    acc10 = __builtin_amdgcn_mfma_f32_16x16x32_bf16(a1h, b0l, acc10, 0, 0, 0);
    acc11 = __builtin_amdgcn_mfma_f32_16x16x32_bf16(a1h, b1h, acc11, 0, 0, 0);
    acc11 = __builtin_amdgcn_mfma_f32_16x16x32_bf16(a1l, b1h, acc11, 0, 0, 0);
    acc11 = __builtin_amdgcn_mfma_f32_16x16x32_bf16(a1h, b1l, acc11, 0, 0, 0);
  }

  // epilogue: C/D layout col=lane&15, row=(lane>>4)*4+reg [m89-verified]
  const int c0 = w * 32 + li;
  const float bv0 = bias[c0];
  const float bv1 = bias[c0 + 16];
#pragma unroll
  for (int reg = 0; reg < 4; ++reg) {
    int r0 = row0 + lg * 4 + reg;
    int r1 = r0 + 16;
    float v;
    unsigned short h;
    v = acc00[reg] + bv0; v = v > 0.f ? v : 0.f;
    h = f2b(v); Ohi[(size_t)r0 * 128 + c0] = h; Olo[(size_t)r0 * 128 + c0] = f2b(v - b2f(h));
    v = acc01[reg] + bv1; v = v > 0.f ? v : 0.f;
    h = f2b(v); Ohi[(size_t)r0 * 128 + c0 + 16] = h; Olo[(size_t)r0 * 128 + c0 + 16] = f2b(v - b2f(h));
    v = acc10[reg] + bv0; v = v > 0.f ? v : 0.f;
    h = f2b(v); Ohi[(size_t)r1 * 128 + c0] = h; Olo[(size_t)r1 * 128 + c0] = f2b(v - b2f(h));
    v = acc11[reg] + bv1; v = v > 0.f ? v : 0.f;
    h = f2b(v); Ohi[(size_t)r1 * 128 + c0 + 16] = h; Olo[(size_t)r1 * 128 + c0 + 16] = f2b(v - b2f(h));
  }
}

// ---------------- layer-4 projection from hi/lo planes ----------------

__global__ __launch_bounds__(256) void k_lastproj(const unsigned short* __restrict__ Hhi,
                                                  const unsigned short* __restrict__ Hlo,
                                                  const float* __restrict__ Wl,
                                                  const float* __restrict__ Wr,
                                                  const float* __restrict__ bias,
                                                  float* __restrict__ U,
                                                  float* __restrict__ V) {
  __shared__ float As[64][132];
  const int t = threadIdx.x;
  const int row0 = blockIdx.x * 64;

#pragma unroll
  for (int i = 0; i < 8; ++i) {
    int idx = i * 256 + t;
    int r = idx >> 5, c4 = idx & 31;
    size_t off = (size_t)(row0 + r) * 128 + c4 * 4;
    ushort4 h = *(const ushort4*)(Hhi + off);
    ushort4 l = *(const ushort4*)(Hlo + off);
    float4 v;
    v.x = b2f(h.x) + b2f(l.x);
    v.y = b2f(h.y) + b2f(l.y);
    v.z = b2f(h.z) + b2f(l.z);
    v.w = b2f(h.w) + b2f(l.w);
    *(float4*)&As[r][c4 * 4] = v;
  }
  __syncthreads();

  const int r = t & 63;
  const int g = t >> 6;
  const bool isV = g >= 2;
  const int st = (g & 1) ? 9 : 0;
  const int cnt = (g & 1) ? 8 : 9;
  const float* __restrict__ W = isV ? Wr : Wl;

  float acc[9];
#pragma unroll
  for (int j = 0; j < 9; ++j) {
    int jj = st + j; if (jj > 16) jj = 16;
    acc[j] = isV ? bias[jj] : 0.f;
  }

#pragma unroll 4
  for (int k4 = 0; k4 < 32; ++k4) {
    float4 a = *(const float4*)&As[r][k4 * 4];
    const float* w0 = W + (size_t)(k4 * 4) * DO + st;
#pragma unroll
    for (int j = 0; j < 9; ++j) {
      int jc = (st + j > 16) ? (16 - st) : j;
      acc[j] = fmaf(a.x, w0[jc], acc[j]);
      acc[j] = fmaf(a.y, w0[DO + jc], acc[j]);
      acc[j] = fmaf(a.z, w0[2 * DO + jc], acc[j]);
      acc[j] = fmaf(a.w, w0[3 * DO + jc], acc[j]);
    }
  }

  float* __restrict__ dstbuf = isV ? V : U;
  const size_t base = (size_t)(row0 + r) * DO + st;
#pragma unroll
  for (int j = 0; j < 9; ++j)
    if (j < cnt) dstbuf[base + j] = acc[j];
}

// ---------------- 17-dim aggregation + epilogue (layer 4) ----------------

__global__ __launch_bounds__(256) void k_agg17(const float* __restrict__ U,
                                               const float* __restrict__ V,
                                               const int* __restrict__ cursor,
                                               const unsigned short* __restrict__ csr,
                                               float* __restrict__ out) {
  int t = blockIdx.x * 256 + threadIdx.x;
  int node = t / DO;
  if (node >= NN) return;
  int ch = t - node * DO;
  int deg = cursor[node];
  int cnt = deg > SLOTS ? SLOTS : deg;
  const unsigned short* idx = csr + ((size_t)node << 6);
  float acc = 0.f;
#define GATH(S, COND) if (COND) acc += U[(size_t)(S)*DO + ch];
  for (int base = 0; base < cnt; base += 8) {
    ushort4 i0 = *(const ushort4*)(idx + base);
    ushort4 i1 = *(const ushort4*)(idx + base + 4);
    GATH(i0.x, true)
    GATH(i0.y, base + 1 < cnt)
    GATH(i0.z, base + 2 < cnt)
    GATH(i0.w, base + 3 < cnt)
    GATH(i1.x, base + 4 < cnt)
    GATH(i1.y, base + 5 < cnt)
    GATH(i1.z, base + 6 < cnt)
    GATH(i1.w, base + 7 < cnt)
  }
#undef GATH
  float inv = 1.0f / (float)(deg > 0 ? deg : 1);
  out[(size_t)node * DO + ch] = fmaxf(fmaf(acc, inv, V[(size_t)node * DO + ch]), 0.f);
}

// ---------------- launch ----------------

extern "C" void kernel_launch(void* const* d_in, const int* in_sizes, int n_in,
                              void* d_out, int out_size, void* d_ws, size_t ws_size,
                              hipStream_t stream) {
  const float* x = (const float*)d_in[0];
  const int* ei = (const int*)d_in[1];  // [2][NE] int32
  const int* src = ei;
  const int* dst = ei + NE;
  const float *wl[5], *bl[5], *wr[5];
  for (int i = 0; i < 5; ++i) {
    wl[i] = (const float*)d_in[2 + 3 * i];
    bl[i] = (const float*)d_in[3 + 3 * i];
    wr[i] = (const float*)d_in[4 + 3 * i];
  }

  char* ws = (char*)d_ws;
  int* cursor = (int*)ws;                      ws += 160256;
  unsigned short* csr = (unsigned short*)ws;   ws += (size_t)NN * SLOTS * 2;  // 5.12 MB
  unsigned short* Hhi = (unsigned short*)ws;   ws += (size_t)NN * DH * 2;     // 10.24 MB
  unsigned short* Hlo = (unsigned short*)ws;   ws += (size_t)NN * DH * 2;     // 10.24 MB
  unsigned short* WThi = (unsigned short*)ws;  ws += (size_t)4 * 128 * 256 * 2;  // 256 KB
  unsigned short* WTlo = (unsigned short*)ws;  ws += (size_t)4 * 128 * 256 * 2;  // 256 KB
  float* M = (float*)ws;                       ws += (size_t)NN * DH * 4;     // 20.48 MB
  float* U = M;   // M dead by layer 4
  float* V = M + (size_t)NN * DO;

  hipMemsetAsync(cursor, 0, NN * sizeof(int), stream);
  k_fill<<<(NE + 255) / 256, 256, 0, stream>>>(src, dst, cursor, csr);
  k_tobf16<<<(NN * 32 + 255) / 256, 256, 0, stream>>>(x, Hhi, Hlo);
  for (int l = 0; l < 4; ++l)
    k_splitw<<<128, 256, 0, stream>>>(wl[l], wr[l], WThi + (size_t)l * 32768,
                                      WTlo + (size_t)l * 32768);

  const int AGG_GRID = (NN * 32 + 255) / 256;  // 5000
  const int GEMM_GRID = NN / 32;               // 1250

  for (int l = 0; l < 4; ++l) {
    k_agg<<<AGG_GRID, 256, 0, stream>>>(Hhi, M, cursor, csr);
    k_gemm_mfma<<<GEMM_GRID, 256, 0, stream>>>(M, Hhi, Hlo,
                                               WThi + (size_t)l * 32768,
                                               WTlo + (size_t)l * 32768,
                                               bl[l], Hhi, Hlo);
  }
  // L4
  k_lastproj<<<NN / 64, 256, 0, stream>>>(Hhi, Hlo, wl[4], wr[4], bl[4], U, V);
  k_agg17<<<(NN * DO + 255) / 256, 256, 0, stream>>>(U, V, cursor, csr,
                                                     (float*)d_out);
}